// Round 1
// baseline (32596.613 us; speedup 1.0000x reference)
//
#include <hip/hip_runtime.h>
#include <stdint.h>

#define B_ 64
#define S_ 512
#define I_ 1024
#define H_ 1024
#define G_ 4096   // 4*H

typedef _Float16 f16;
typedef _Float16 f16x8 __attribute__((ext_vector_type(8)));
typedef _Float16 f16x4v __attribute__((ext_vector_type(4)));
typedef float f32x4 __attribute__((ext_vector_type(4)));

__device__ __forceinline__ f32x4 mfma16(f16x8 a, f16x8 b, f32x4 c) {
    return __builtin_amdgcn_mfma_f32_16x16x32_f16(a, b, c, 0, 0, 0);
}

__device__ __forceinline__ float sigm(float x)  { return 1.f / (1.f + __expf(-x)); }
__device__ __forceinline__ float tanh_(float x) { return 1.f - 2.f / (1.f + __expf(2.f * x)); }

// ---------------------------------------------------------------------------
// tf_mask dtype detector: 1 => 4-byte elems (int32 or float32; int32!=0 test
// is correct for both), 0 => 1-byte elems. Reads only first 512 bytes (safe
// for both layouts). Deterministic given fixed input.
// ---------------------------------------------------------------------------
__global__ void detect_mask(const unsigned int* __restrict__ m, int* __restrict__ flag) {
    __shared__ int ok;
    if (threadIdx.x == 0) ok = 1;
    __syncthreads();
    unsigned w = m[threadIdx.x];                    // 128 threads -> 512 bytes
    bool is4 = (w == 0u) || (w == 1u) || (w == 0x3F800000u);
    if (!is4) atomicAnd(&ok, 0);
    __syncthreads();
    if (threadIdx.x == 0) *flag = ok;
}

// f32 -> f16 cast, 4 elems/thread
__global__ void cast_f32_f16(const float* __restrict__ src, f16* __restrict__ dst, int n4) {
    int i = blockIdx.x * blockDim.x + threadIdx.x;
    if (i >= n4) return;
    float4 v = reinterpret_cast<const float4*>(src)[i];
    f16x4v t = {(f16)v.x, (f16)v.y, (f16)v.z, (f16)v.w};
    reinterpret_cast<f16x4v*>(dst)[i] = t;
}

// ---------------------------------------------------------------------------
// One LSTM step. Grid 128 blocks x 128 threads.
//   bid = mhalf*64 + k   (same-k pair 64 apart -> likely same XCD for W reuse)
//   block owns h-cols [16k,16k+16) x batch rows [32*mhalf, 32*mhalf+32)
//   wave (2/block) owns one 16-row M-tile; computes all 4 gate tiles.
// A source: either f32 (row stride astride) or f16 (row stride astride).
// gates = A @ Wih^T + h_in @ Whh^T + bias ; then cell update; h_out f16.
// ---------------------------------------------------------------------------
__global__ __launch_bounds__(128) void cell_kernel(
    const float* __restrict__ Af, const f16* __restrict__ Ab, long astride,
    const f16* __restrict__ Wih, const f16* __restrict__ Whh,
    const float* __restrict__ bias,
    const f16* __restrict__ hin, f16* __restrict__ hout, float* __restrict__ cbuf)
{
    const int bid   = blockIdx.x;
    const int k     = bid & 63;
    const int mhalf = bid >> 6;
    const int wave  = (threadIdx.x >> 6) & 1;
    const int lane  = threadIdx.x & 63;
    const int r     = lane & 15;      // A row-in-tile / B col-in-tile / C col
    const int q     = lane >> 4;      // k-quad: k offset q*8
    const int mrow  = mhalf * 32 + wave * 16 + r;
    const int col   = k * 16 + r;     // h-column this lane serves

    f32x4 acc0 = {0.f,0.f,0.f,0.f}, acc1 = {0.f,0.f,0.f,0.f};
    f32x4 acc2 = {0.f,0.f,0.f,0.f}, acc3 = {0.f,0.f,0.f,0.f};

    const f16* w0 = Wih + (long)(0 * H_ + col) * I_ + q * 8;
    const f16* w1 = Wih + (long)(1 * H_ + col) * I_ + q * 8;
    const f16* w2 = Wih + (long)(2 * H_ + col) * I_ + q * 8;
    const f16* w3 = Wih + (long)(3 * H_ + col) * I_ + q * 8;

    if (Af) {  // f32 input rows (x or x[:, -1, :])
        const float* ar = Af + (long)mrow * astride + q * 8;
        #pragma unroll 4
        for (int kb = 0; kb < 32; ++kb) {
            const float* p = ar + kb * 32;
            float4 u = *reinterpret_cast<const float4*>(p);
            float4 v = *reinterpret_cast<const float4*>(p + 4);
            f16x8 a = {(f16)u.x, (f16)u.y, (f16)u.z, (f16)u.w,
                       (f16)v.x, (f16)v.y, (f16)v.z, (f16)v.w};
            acc0 = mfma16(a, *reinterpret_cast<const f16x8*>(w0 + kb * 32), acc0);
            acc1 = mfma16(a, *reinterpret_cast<const f16x8*>(w1 + kb * 32), acc1);
            acc2 = mfma16(a, *reinterpret_cast<const f16x8*>(w2 + kb * 32), acc2);
            acc3 = mfma16(a, *reinterpret_cast<const f16x8*>(w3 + kb * 32), acc3);
        }
    } else {   // f16 input rows (decoder feedback buffer)
        const f16* ar = Ab + (long)mrow * astride + q * 8;
        #pragma unroll 4
        for (int kb = 0; kb < 32; ++kb) {
            f16x8 a = *reinterpret_cast<const f16x8*>(ar + kb * 32);
            acc0 = mfma16(a, *reinterpret_cast<const f16x8*>(w0 + kb * 32), acc0);
            acc1 = mfma16(a, *reinterpret_cast<const f16x8*>(w1 + kb * 32), acc1);
            acc2 = mfma16(a, *reinterpret_cast<const f16x8*>(w2 + kb * 32), acc2);
            acc3 = mfma16(a, *reinterpret_cast<const f16x8*>(w3 + kb * 32), acc3);
        }
    }

    // recurrent part: h_in @ Whh^T
    {
        const f16* v0 = Whh + (long)(0 * H_ + col) * H_ + q * 8;
        const f16* v1 = Whh + (long)(1 * H_ + col) * H_ + q * 8;
        const f16* v2 = Whh + (long)(2 * H_ + col) * H_ + q * 8;
        const f16* v3 = Whh + (long)(3 * H_ + col) * H_ + q * 8;
        const f16* hr = hin + (long)mrow * H_ + q * 8;
        #pragma unroll 4
        for (int kb = 0; kb < 32; ++kb) {
            f16x8 a = *reinterpret_cast<const f16x8*>(hr + kb * 32);
            acc0 = mfma16(a, *reinterpret_cast<const f16x8*>(v0 + kb * 32), acc0);
            acc1 = mfma16(a, *reinterpret_cast<const f16x8*>(v1 + kb * 32), acc1);
            acc2 = mfma16(a, *reinterpret_cast<const f16x8*>(v2 + kb * 32), acc2);
            acc3 = mfma16(a, *reinterpret_cast<const f16x8*>(v3 + kb * 32), acc3);
        }
    }

    // epilogue: C/D layout col = lane&15, row = q*4 + t (+ tile M offset)
    const float bi = bias[0 * H_ + col];
    const float bf = bias[1 * H_ + col];
    const float bg = bias[2 * H_ + col];
    const float bo = bias[3 * H_ + col];
    #pragma unroll
    for (int t = 0; t < 4; ++t) {
        const int  br  = mhalf * 32 + wave * 16 + q * 4 + t;
        const long idx = (long)br * H_ + col;
        float iv = sigm(acc0[t] + bi);
        float fv = sigm(acc1[t] + bf);
        float gv = tanh_(acc2[t] + bg);
        float ov = sigm(acc3[t] + bo);
        float cn = fv * cbuf[idx] + iv * gv;
        cbuf[idx] = cn;
        hout[idx] = (f16)(ov * tanh_(cn));
    }
}

// ---------------------------------------------------------------------------
// Decoder head: pred = h @ fc_W^T + fc_b ; write pred f32 to out;
// next input = tf_mask[s] ? target_s : pred (as f16).
// Grid 64 blocks x 256 threads; block owns fc cols [16k,16k+16), wave an M-tile.
// ---------------------------------------------------------------------------
__global__ __launch_bounds__(256) void pred_kernel(
    const f16* __restrict__ h, const f16* __restrict__ fcW, const float* __restrict__ fcb,
    float* __restrict__ outbase /* d_out + s*I */, const float* __restrict__ tgt /* target + s*I */,
    f16* __restrict__ nxt, const unsigned char* __restrict__ mask, const int* __restrict__ flag,
    int s)
{
    const int k    = blockIdx.x;
    const int wave = threadIdx.x >> 6;
    const int lane = threadIdx.x & 63;
    const int r    = lane & 15, q = lane >> 4;
    const int mrow = wave * 16 + r;
    const int col  = k * 16 + r;

    f32x4 acc = {0.f,0.f,0.f,0.f};
    const f16* hr = h   + (long)mrow * H_ + q * 8;
    const f16* wr = fcW + (long)col  * H_ + q * 8;
    #pragma unroll 4
    for (int kb = 0; kb < 32; ++kb)
        acc = mfma16(*reinterpret_cast<const f16x8*>(hr + kb * 32),
                     *reinterpret_cast<const f16x8*>(wr + kb * 32), acc);

    const bool m = (*flag) ? (reinterpret_cast<const int*>(mask)[s] != 0)
                           : (mask[s] != 0);
    const float bb = fcb[col];
    #pragma unroll
    for (int t = 0; t < 4; ++t) {
        const int br = wave * 16 + q * 4 + t;
        float p = acc[t] + bb;
        outbase[(long)br * (S_ * I_) + col] = p;
        float nv = m ? tgt[(long)br * (S_ * I_) + col] : p;
        nxt[(long)br * I_ + col] = (f16)nv;
    }
}

// ---------------------------------------------------------------------------
extern "C" void kernel_launch(void* const* d_in, const int* in_sizes, int n_in,
                              void* d_out, int out_size, void* d_ws, size_t ws_size,
                              hipStream_t stream) {
    (void)in_sizes; (void)n_in; (void)out_size; (void)ws_size;
    const float* x       = (const float*)d_in[0];
    const float* target  = (const float*)d_in[1];
    const float* enc_Wih = (const float*)d_in[2];
    const float* enc_Whh = (const float*)d_in[3];
    const float* enc_b   = (const float*)d_in[4];
    const float* dec_Wih = (const float*)d_in[5];
    const float* dec_Whh = (const float*)d_in[6];
    const float* dec_b   = (const float*)d_in[7];
    const float* fc_W    = (const float*)d_in[8];
    const float* fc_b    = (const float*)d_in[9];
    const void*  tfmask  = d_in[10];

    uint8_t* p = (uint8_t*)d_ws;
    auto carve = [&](size_t bytes) { void* r = (void*)p; p += (bytes + 255) & ~(size_t)255; return r; };
    f16*   Wihe = (f16*)carve((size_t)G_ * I_ * 2);
    f16*   Whhe = (f16*)carve((size_t)G_ * H_ * 2);
    f16*   Wihd = (f16*)carve((size_t)G_ * I_ * 2);
    f16*   Whhd = (f16*)carve((size_t)G_ * H_ * 2);
    f16*   fcWh = (f16*)carve((size_t)I_ * H_ * 2);
    f16*   h0   = (f16*)carve((size_t)B_ * H_ * 2);
    f16*   h1   = (f16*)carve((size_t)B_ * H_ * 2);
    f16*   nxt  = (f16*)carve((size_t)B_ * I_ * 2);
    float* cbuf = (float*)carve((size_t)B_ * H_ * 4);
    int*   flag = (int*)carve(256);

    detect_mask<<<1, 128, 0, stream>>>((const unsigned int*)tfmask, flag);

    const int n4w = G_ * I_ / 4;   // 1,048,576
    const int n4f = I_ * H_ / 4;   //   262,144
    cast_f32_f16<<<(n4w + 255) / 256, 256, 0, stream>>>(enc_Wih, Wihe, n4w);
    cast_f32_f16<<<(n4w + 255) / 256, 256, 0, stream>>>(enc_Whh, Whhe, n4w);
    cast_f32_f16<<<(n4w + 255) / 256, 256, 0, stream>>>(dec_Wih, Wihd, n4w);
    cast_f32_f16<<<(n4w + 255) / 256, 256, 0, stream>>>(dec_Whh, Whhd, n4w);
    cast_f32_f16<<<(n4f + 255) / 256, 256, 0, stream>>>(fc_W,    fcWh, n4f);

    hipMemsetAsync(h0,   0, (size_t)B_ * H_ * 2, stream);
    hipMemsetAsync(cbuf, 0, (size_t)B_ * H_ * 4, stream);

    f16 *hin = h0, *hout = h1;

    // encoder: 512 steps, input x[:, s, :] (f32, row stride S*I)
    for (int s = 0; s < S_; ++s) {
        cell_kernel<<<128, 128, 0, stream>>>(x + (long)s * I_, (const f16*)nullptr, (long)S_ * I_,
                                             Wihe, Whhe, enc_b, hin, hout, cbuf);
        f16* t_ = hin; hin = hout; hout = t_;
    }

    // decoder: 512 steps
    for (int t = 0; t < S_; ++t) {
        if (t == 0) {
            cell_kernel<<<128, 128, 0, stream>>>(x + (long)(S_ - 1) * I_, (const f16*)nullptr, (long)S_ * I_,
                                                 Wihd, Whhd, dec_b, hin, hout, cbuf);
        } else {
            cell_kernel<<<128, 128, 0, stream>>>((const float*)nullptr, nxt, (long)I_,
                                                 Wihd, Whhd, dec_b, hin, hout, cbuf);
        }
        pred_kernel<<<64, 256, 0, stream>>>(hout, fcWh, fc_b,
                                            (float*)d_out + (long)t * I_,
                                            target + (long)t * I_,
                                            nxt, (const unsigned char*)tfmask, flag, t);
        f16* t_ = hin; hin = hout; hout = t_;
    }
}